// Round 2
// baseline (385.782 us; speedup 1.0000x reference)
//
#include <hip/hip_runtime.h>

#define B_ 8
#define L_ 4800
#define H_ 8
#define D_ 64
#define BH_ 64

// Workspace layout (float offsets)
#define G_ELEMS (BH_*D_*D_)          // 262144
#define QSQ_OFF G_ELEMS              // 262144
#define KSQ_OFF (QSQ_OFF + BH_*D_)   // 266240
#define M_OFF   (KSQ_OFF + BH_*D_)   // 270336

#define NCH 25
#define CHUNK 192                    // 12 slabs of 16 rows
#define NSLAB 12

// ---------------------------------------------------------------------------
// Kernel A: per (b,h) Gram matrix G = q^T k over L (chunked), plus sum-of-
// squares of q and k rows.  Ping-pong LDS double-buffer, ONE barrier per
// 16-row slab; global prefetch for slab s+1 issues before compute of slab s.
// ---------------------------------------------------------------------------
__global__ __launch_bounds__(256) void gram_kernel(
    const float* __restrict__ q, const float* __restrict__ k,
    float* __restrict__ G, float* __restrict__ qsq, float* __restrict__ ksq)
{
  const int bh = blockIdx.y;
  const int b = bh >> 3, h = bh & 7;
  const int l0 = blockIdx.x * CHUNK;
  const int t = threadIdx.x;
  const int tx = t & 15, ty = t >> 4;   // 16x16 thread tile -> 4x4 G elements

  __shared__ float Lq[2][16][64];
  __shared__ float Lk[2][16][64];

  // staging: each thread loads one float4 of q AND one of k per 16-row slab
  const int sr = t >> 4;               // 0..15 (row in slab)
  const int sc = (t & 15) * 4;         // 0..60 (d offset)
  const float* qp = q + (((size_t)(b*L_ + l0 + sr))*H_ + h)*D_ + sc;
  const float* kp = k + (((size_t)(b*L_ + l0 + sr))*H_ + h)*D_ + sc;
  const size_t step = (size_t)16*H_*D_;

  float sq[4] = {0,0,0,0}, sk[4] = {0,0,0,0};
  float acc[4][4] = {};

  // preload slab 0
  float4 rq = *(const float4*)qp; qp += step;
  float4 rk = *(const float4*)kp; kp += step;
  *(float4*)&Lq[0][sr][sc] = rq;
  *(float4*)&Lk[0][sr][sc] = rk;
  sq[0] += rq.x*rq.x; sq[1] += rq.y*rq.y; sq[2] += rq.z*rq.z; sq[3] += rq.w*rq.w;
  sk[0] += rk.x*rk.x; sk[1] += rk.y*rk.y; sk[2] += rk.z*rk.z; sk[3] += rk.w*rk.w;
  __syncthreads();

  for (int s = 0; s < NSLAB; s++) {
    const int cur = s & 1;
    if (s + 1 < NSLAB) {               // issue next-slab loads early
      rq = *(const float4*)qp; qp += step;
      rk = *(const float4*)kp; kp += step;
    }
#pragma unroll
    for (int r = 0; r < 16; r++) {
      float4 qa4 = *(const float4*)&Lq[cur][r][ty*4];
      float4 kb4 = *(const float4*)&Lk[cur][r][tx*4];
      float qa[4] = {qa4.x,qa4.y,qa4.z,qa4.w};
      float kb[4] = {kb4.x,kb4.y,kb4.z,kb4.w};
#pragma unroll
      for (int i = 0; i < 4; i++)
#pragma unroll
        for (int j = 0; j < 4; j++)
          acc[i][j] = fmaf(qa[i], kb[j], acc[i][j]);
    }
    if (s + 1 < NSLAB) {
      // safe: all threads passed the barrier ending iter s-1, so no one still
      // reads buf cur^1; this store overlaps with other threads' compute on cur
      *(float4*)&Lq[cur^1][sr][sc] = rq;
      *(float4*)&Lk[cur^1][sr][sc] = rk;
      sq[0] += rq.x*rq.x; sq[1] += rq.y*rq.y; sq[2] += rq.z*rq.z; sq[3] += rq.w*rq.w;
      sk[0] += rk.x*rk.x; sk[1] += rk.y*rk.y; sk[2] += rk.z*rk.z; sk[3] += rk.w*rk.w;
      __syncthreads();
    }
  }

  // block-level reduction of sum-of-squares via LDS (slab buffers as scratch)
  *(float4*)&Lq[0][sr][sc] = make_float4(sq[0], sq[1], sq[2], sq[3]);
  *(float4*)&Lk[0][sr][sc] = make_float4(sk[0], sk[1], sk[2], sk[3]);
  __syncthreads();
  if (t < 64) {
    float s = 0.f;
#pragma unroll
    for (int r = 0; r < 16; r++) s += Lq[0][r][t];
    atomicAdd(&qsq[bh*64 + t], s);
  } else if (t < 128) {
    const int d = t - 64;
    float s = 0.f;
#pragma unroll
    for (int r = 0; r < 16; r++) s += Lk[0][r][d];
    atomicAdd(&ksq[bh*64 + d], s);
  }

  float* g = G + (size_t)bh*4096;
#pragma unroll
  for (int i = 0; i < 4; i++)
#pragma unroll
    for (int j = 0; j < 4; j++)
      atomicAdd(&g[(ty*4+i)*64 + tx*4 + j], acc[i][j]);
}

// ---------------------------------------------------------------------------
// Kernel B: per (b,h) 64x64 postprocessing: normalize, gates, temperature,
// 4x exact top-k (rank counting, tie-exact) + masked softmax, combine into M.
// ---------------------------------------------------------------------------
__global__ __launch_bounds__(256) void mask_kernel(
    const float* __restrict__ G, const float* __restrict__ qsq,
    const float* __restrict__ ksq,
    const float* __restrict__ temperature, const float* __restrict__ attns,
    const float* __restrict__ row_w, const float* __restrict__ row_b,
    const float* __restrict__ col_w, const float* __restrict__ col_b,
    float* __restrict__ M)
{
  const int bh = blockIdx.x;
  const int h = bh & 7;
  const int t = threadIdx.x;
  const int d = t & 63, q4 = t >> 6;
  const int e0 = q4 * 16;

  __shared__ float att[64][65];
  __shared__ float rnq[64], rnk[64], cw[64], rw[64];
  __shared__ float wcol[64], wrow[64];
  __shared__ float thr[4][64];
  __shared__ float pmax[4][64];
  __shared__ float rowmax[64];
  __shared__ float psum[4][4][64];
  __shared__ float rinv[4][64];

  if (t < 64)        rnq[t]     = 1.0f / fmaxf(sqrtf(qsq[bh*64 + t]), 1e-12f);
  else if (t < 128)  rnk[t-64]  = 1.0f / fmaxf(sqrtf(ksq[bh*64 + t-64]), 1e-12f);
  else if (t < 192)  cw[t-128]  = col_w[t-128];
  else               rw[t-192]  = row_w[t-192];
  __syncthreads();

  {
    const float* gp = G + (size_t)bh*4096 + d*64 + e0;
    float rq = rnq[d];
#pragma unroll
    for (int ee = 0; ee < 16; ee++)
      att[d][e0+ee] = gp[ee] * rq * rnk[e0+ee];
  }
  __syncthreads();

  if (t < 64) {
    float s = 0.f;
    for (int c = 0; c < 64; c++) s += att[c][t] * cw[c];
    s += col_b[0];
    wcol[t] = 1.0f / (1.0f + __expf(-s));
  } else if (t < 128) {
    int c = t - 64;
    float s = 0.f;
    for (int e = 0; e < 64; e++) s += att[c][e] * rw[e];
    s += row_b[0];
    wrow[c] = 1.0f / (1.0f + __expf(-s));
  }
  __syncthreads();

  {
    const float temp = temperature[h];
    const float wr = wrow[d];
    float mx = -1e30f;
#pragma unroll
    for (int ee = 0; ee < 16; ee++) {
      float x = att[d][e0+ee] * ((wcol[e0+ee] + wr) * temp);
      att[d][e0+ee] = x;
      mx = fmaxf(mx, x);
    }
    pmax[q4][d] = mx;
  }
  __syncthreads();
  if (t < 64)
    rowmax[t] = fmaxf(fmaxf(pmax[0][t], pmax[1][t]), fmaxf(pmax[2][t], pmax[3][t]));

  // exact k-th largest by rank counting (tie-exact like lax.top_k)
  {
    float x[16];
#pragma unroll
    for (int j = 0; j < 16; j++) x[j] = att[d][e0+j];
    int gt[16] = {}, ge[16] = {};
    for (int m = 0; m < 64; m++) {
      float y = att[d][m];
#pragma unroll
      for (int j = 0; j < 16; j++) { gt[j] += (y > x[j]); ge[j] += (y >= x[j]); }
    }
    const int tks[4] = {32, 42, 48, 51};
#pragma unroll
    for (int j = 0; j < 16; j++)
#pragma unroll
      for (int i = 0; i < 4; i++)
        if (gt[j] <= tks[i]-1 && ge[j] >= tks[i]) thr[i][d] = x[j];
  }
  __syncthreads();

  {
    const float rm = rowmax[d];
    const float t0 = thr[0][d], t1 = thr[1][d], t2 = thr[2][d], t3 = thr[3][d];
    float s0=0.f, s1=0.f, s2=0.f, s3=0.f;
#pragma unroll
    for (int ee = 0; ee < 16; ee++) {
      float xv = att[d][e0+ee];
      float ex = __expf(xv - rm);
      if (xv >= t0) s0 += ex;
      if (xv >= t1) s1 += ex;
      if (xv >= t2) s2 += ex;
      if (xv >= t3) s3 += ex;
    }
    psum[q4][0][d] = s0; psum[q4][1][d] = s1; psum[q4][2][d] = s2; psum[q4][3][d] = s3;
  }
  __syncthreads();
  if (t < 64) {
#pragma unroll
    for (int i = 0; i < 4; i++) {
      float s = psum[0][i][t] + psum[1][i][t] + psum[2][i][t] + psum[3][i][t];
      rinv[i][t] = attns[i] / s;
    }
  }
  __syncthreads();

  {
    const float rm = rowmax[d];
    const float t0 = thr[0][d], t1 = thr[1][d], t2 = thr[2][d], t3 = thr[3][d];
    const float r0 = rinv[0][d], r1 = rinv[1][d], r2 = rinv[2][d], r3 = rinv[3][d];
    float* mo = M + (size_t)bh*4096 + d*64 + e0;
#pragma unroll
    for (int ee = 0; ee < 16; ee++) {
      float xv = att[d][e0+ee];
      float ex = __expf(xv - rm);
      float m = 0.f;
      if (xv >= t0) m += r0 * ex;
      if (xv >= t1) m += r1 * ex;
      if (xv >= t2) m += r2 * ex;
      if (xv >= t3) m += r3 * ex;
      mo[ee] = m;
    }
  }
}

// ---------------------------------------------------------------------------
// Kernel C: out[b,l,h,:] = M_bh * v[b,l,h,:].  Block = (b,h) x 192 l's in
// 3 tiles of 64; M staged once per block, v ping-pong double-buffered.
// ---------------------------------------------------------------------------
#define ATILES 3
#define ABLK 25                       // 25 blocks per bh x 192 l's = 4800

__global__ __launch_bounds__(256) void apply_kernel(
    const float* __restrict__ M, const float* __restrict__ v,
    float* __restrict__ out)
{
  const int bh = blockIdx.y;
  const int b = bh >> 3, h = bh & 7;
  const int lbase = blockIdx.x * (64 * ATILES);
  const int t = threadIdx.x;

  __shared__ float Ms[64][68];        // [e][d] (transposed)
  __shared__ float Vs[2][64][68];     // [l][e]

  const int dd = t >> 4;              // hmm: used for M staging rows below
  const int c4 = (t & 15) * 4;

  // stage M transposed: 4 float4 rows per thread
#pragma unroll
  for (int i = 0; i < 4; i++) {
    int row = dd + i*16;              // 0..63
    float4 mv = *(const float4*)(M + (size_t)bh*4096 + row*64 + c4);
    Ms[c4+0][row] = mv.x; Ms[c4+1][row] = mv.y;
    Ms[c4+2][row] = mv.z; Ms[c4+3][row] = mv.w;
  }

  // preload v tile 0
  float4 pv[4];
#pragma unroll
  for (int i = 0; i < 4; i++)
    pv[i] = *(const float4*)(v + (((size_t)b*L_ + lbase + dd + i*16)*H_ + h)*D_ + c4);
#pragma unroll
  for (int i = 0; i < 4; i++)
    *(float4*)&Vs[0][dd + i*16][c4] = pv[i];
  __syncthreads();

  const int dq = t & 15, lq = t >> 4;
  const int d0 = dq * 4, lr = lq * 4;

  for (int s = 0; s < ATILES; s++) {
    const int cur = s & 1;
    if (s + 1 < ATILES) {
#pragma unroll
      for (int i = 0; i < 4; i++)
        pv[i] = *(const float4*)(v + (((size_t)b*L_ + lbase + (s+1)*64 + dd + i*16)*H_ + h)*D_ + c4);
    }

    float acc[4][4] = {};             // [i=d][j=l]
#pragma unroll
    for (int e4 = 0; e4 < 16; e4++) {
      const int e = e4 * 4;
      float4 m0 = *(const float4*)&Ms[e+0][d0];
      float4 m1 = *(const float4*)&Ms[e+1][d0];
      float4 m2 = *(const float4*)&Ms[e+2][d0];
      float4 m3 = *(const float4*)&Ms[e+3][d0];
      float ma[4][4] = {{m0.x,m0.y,m0.z,m0.w},{m1.x,m1.y,m1.z,m1.w},
                        {m2.x,m2.y,m2.z,m2.w},{m3.x,m3.y,m3.z,m3.w}};
#pragma unroll
      for (int j = 0; j < 4; j++) {
        float4 vj = *(const float4*)&Vs[cur][lr+j][e];
        float va[4] = {vj.x, vj.y, vj.z, vj.w};
#pragma unroll
        for (int i = 0; i < 4; i++) {
          acc[i][j] = fmaf(ma[0][i], va[0], acc[i][j]);
          acc[i][j] = fmaf(ma[1][i], va[1], acc[i][j]);
          acc[i][j] = fmaf(ma[2][i], va[2], acc[i][j]);
          acc[i][j] = fmaf(ma[3][i], va[3], acc[i][j]);
        }
      }
    }

#pragma unroll
    for (int j = 0; j < 4; j++) {
      int l = lbase + s*64 + lr + j;
      float4 o = make_float4(acc[0][j], acc[1][j], acc[2][j], acc[3][j]);
      *(float4*)(out + (((size_t)b*L_ + l)*H_ + h)*D_ + d0) = o;
    }

    if (s + 1 < ATILES) {
      // safe: barrier ending iter s-1 guarantees no reader of buf cur^1 remains
#pragma unroll
      for (int i = 0; i < 4; i++)
        *(float4*)&Vs[cur^1][dd + i*16][c4] = pv[i];
      __syncthreads();
    }
  }
}

// ---------------------------------------------------------------------------
extern "C" void kernel_launch(void* const* d_in, const int* in_sizes, int n_in,
                              void* d_out, int out_size, void* d_ws, size_t ws_size,
                              hipStream_t stream) {
  const float* q           = (const float*)d_in[0];
  const float* k           = (const float*)d_in[1];
  const float* v           = (const float*)d_in[2];
  const float* temperature = (const float*)d_in[3];
  const float* attns       = (const float*)d_in[4];
  const float* row_w       = (const float*)d_in[5];
  const float* row_b       = (const float*)d_in[6];
  const float* col_w       = (const float*)d_in[7];
  const float* col_b       = (const float*)d_in[8];
  float* out = (float*)d_out;

  float* ws  = (float*)d_ws;
  float* G   = ws;
  float* qsq = ws + QSQ_OFF;
  float* ksq = ws + KSQ_OFF;
  float* M   = ws + M_OFF;

  hipMemsetAsync(ws, 0, (size_t)M_OFF * sizeof(float), stream);

  gram_kernel<<<dim3(NCH, BH_), 256, 0, stream>>>(q, k, G, qsq, ksq);
  mask_kernel<<<dim3(BH_), 256, 0, stream>>>(G, qsq, ksq, temperature, attns,
                                             row_w, row_b, col_w, col_b, M);
  apply_kernel<<<dim3(ABLK, BH_), 256, 0, stream>>>(M, v, out);
}

// Round 3
// 305.791 us; speedup vs baseline: 1.2616x; 1.2616x over previous
//
#include <hip/hip_runtime.h>

#define B_ 8
#define L_ 4800
#define H_ 8
#define D_ 64
#define BH_ 64

#define NCH 15
#define CHUNK 320          // L-span per gram block (divisible by 4 waves * SLAB)
#define SLAB 8             // rows per wave-slab
#define WSLABS 10          // CHUNK / (SLAB*4)

// workspace layout (float offsets)
#define GP_SIZE   (BH_*NCH*4096)            // 3,932,160
#define QSQP_OFF  GP_SIZE
#define QSQP_SIZE (BH_*NCH*64)              // 61,440
#define KSQP_OFF  (QSQP_OFF + QSQP_SIZE)
#define M_OFF     (KSQP_OFF + QSQP_SIZE)    // total ~17.3 MB + 1 MB

// ---------------------------------------------------------------------------
// Kernel A: per (b,h,chunk) partial Gram G = q^T k, plus partial sum-of-
// squares.  Wave-synchronous: each wave owns private LDS slabs and an 8x8
// register tile; NO barriers in the K-loop, NO atomics anywhere.
// ---------------------------------------------------------------------------
__global__ __launch_bounds__(256) void gram_kernel(
    const float* __restrict__ q, const float* __restrict__ k,
    float* __restrict__ Gp, float* __restrict__ qsqp, float* __restrict__ ksqp)
{
  const int bh = blockIdx.y;
  const int b = bh >> 3, h = bh & 7;
  const int cx = blockIdx.x;
  const int l0 = cx * CHUNK;
  const int t = threadIdx.x;
  const int w = t >> 6, lane = t & 63;

  __shared__ float Ls[4][2][2][SLAB][64];   // [wave][buf][q/k][row][d] = 32 KB

  const int lrow = lane >> 4;          // 0..3 (row within half-slab)
  const int lcol = (lane & 15) * 4;    // 0..60
  const int r0 = (lane >> 3) * 8;      // acc tile rows
  const int c0 = (lane & 7) * 8;       // acc tile cols

  const float* qb = q + (size_t)(b*L_)*512 + h*64;
  const float* kb = k + (size_t)(b*L_)*512 + h*64;

  float accG[8][8] = {};
  float sqq[4] = {0,0,0,0}, sqk[4] = {0,0,0,0};

  // preload + stage slab 0 (wave's slabs: l0 + (w + 4*s)*SLAB)
  {
    const int ls = l0 + w*SLAB;
    const float* qp = qb + (size_t)(ls + lrow)*512 + lcol;
    const float* kp = kb + (size_t)(ls + lrow)*512 + lcol;
    float4 a0 = *(const float4*)qp;
    float4 a1 = *(const float4*)(qp + 4*512);
    float4 b0 = *(const float4*)kp;
    float4 b1 = *(const float4*)(kp + 4*512);
    sqq[0]+=a0.x*a0.x; sqq[1]+=a0.y*a0.y; sqq[2]+=a0.z*a0.z; sqq[3]+=a0.w*a0.w;
    sqq[0]+=a1.x*a1.x; sqq[1]+=a1.y*a1.y; sqq[2]+=a1.z*a1.z; sqq[3]+=a1.w*a1.w;
    sqk[0]+=b0.x*b0.x; sqk[1]+=b0.y*b0.y; sqk[2]+=b0.z*b0.z; sqk[3]+=b0.w*b0.w;
    sqk[0]+=b1.x*b1.x; sqk[1]+=b1.y*b1.y; sqk[2]+=b1.z*b1.z; sqk[3]+=b1.w*b1.w;
    *(float4*)&Ls[w][0][0][lrow  ][lcol] = a0;
    *(float4*)&Ls[w][0][0][lrow+4][lcol] = a1;
    *(float4*)&Ls[w][0][1][lrow  ][lcol] = b0;
    *(float4*)&Ls[w][0][1][lrow+4][lcol] = b1;
  }

  for (int s = 0; s < WSLABS; s++) {
    const int cur = s & 1;
    float4 a0, a1, b0, b1;
    if (s + 1 < WSLABS) {               // issue next-slab global loads early
      const int ls = l0 + (w + 4*(s+1))*SLAB;
      const float* qp = qb + (size_t)(ls + lrow)*512 + lcol;
      const float* kp = kb + (size_t)(ls + lrow)*512 + lcol;
      a0 = *(const float4*)qp;
      a1 = *(const float4*)(qp + 4*512);
      b0 = *(const float4*)kp;
      b1 = *(const float4*)(kp + 4*512);
    }
    // compute current slab (wave-private; compiler inserts lgkmcnt only)
    const float (*Lq)[64] = Ls[w][cur][0];
    const float (*Lk)[64] = Ls[w][cur][1];
#pragma unroll
    for (int r = 0; r < SLAB; r++) {
      float4 qa0 = *(const float4*)&Lq[r][r0];
      float4 qa1 = *(const float4*)&Lq[r][r0+4];
      float4 kb0 = *(const float4*)&Lk[r][c0];
      float4 kb1 = *(const float4*)&Lk[r][c0+4];
      float av[8] = {qa0.x,qa0.y,qa0.z,qa0.w,qa1.x,qa1.y,qa1.z,qa1.w};
      float bv[8] = {kb0.x,kb0.y,kb0.z,kb0.w,kb1.x,kb1.y,kb1.z,kb1.w};
#pragma unroll
      for (int i = 0; i < 8; i++)
#pragma unroll
        for (int j = 0; j < 8; j++)
          accG[i][j] = fmaf(av[i], bv[j], accG[i][j]);
    }
    if (s + 1 < WSLABS) {
      sqq[0]+=a0.x*a0.x; sqq[1]+=a0.y*a0.y; sqq[2]+=a0.z*a0.z; sqq[3]+=a0.w*a0.w;
      sqq[0]+=a1.x*a1.x; sqq[1]+=a1.y*a1.y; sqq[2]+=a1.z*a1.z; sqq[3]+=a1.w*a1.w;
      sqk[0]+=b0.x*b0.x; sqk[1]+=b0.y*b0.y; sqk[2]+=b0.z*b0.z; sqk[3]+=b0.w*b0.w;
      sqk[0]+=b1.x*b1.x; sqk[1]+=b1.y*b1.y; sqk[2]+=b1.z*b1.z; sqk[3]+=b1.w*b1.w;
      *(float4*)&Ls[w][cur^1][0][lrow  ][lcol] = a0;
      *(float4*)&Ls[w][cur^1][0][lrow+4][lcol] = a1;
      *(float4*)&Ls[w][cur^1][1][lrow  ][lcol] = b0;
      *(float4*)&Ls[w][cur^1][1][lrow+4][lcol] = b1;
    }
  }

  // ---- cross-wave reduction (staging LDS reused as 4 x 2048-float scratch) ----
  float* red = &Ls[0][0][0][0][0];
  float4* redf4 = (float4*)red;
  float* gout = Gp + ((size_t)bh*NCH + cx)*4096;

  __syncthreads();
  // pass A: global rows 0..31
  if (r0 < 32) {
#pragma unroll
    for (int i = 0; i < 8; i++) {
      *(float4*)&red[w*2048 + (r0+i)*64 + c0    ] = make_float4(accG[i][0],accG[i][1],accG[i][2],accG[i][3]);
      *(float4*)&red[w*2048 + (r0+i)*64 + c0 + 4] = make_float4(accG[i][4],accG[i][5],accG[i][6],accG[i][7]);
    }
  }
  __syncthreads();
#pragma unroll
  for (int pp = 0; pp < 2; pp++) {
    int fi = t + pp*256;
    float4 s0 = redf4[fi], s1 = redf4[512+fi], s2 = redf4[1024+fi], s3 = redf4[1536+fi];
    float4 r; r.x = s0.x+s1.x+s2.x+s3.x; r.y = s0.y+s1.y+s2.y+s3.y;
    r.z = s0.z+s1.z+s2.z+s3.z; r.w = s0.w+s1.w+s2.w+s3.w;
    *(float4*)&gout[fi*4] = r;
  }
  __syncthreads();
  // pass B: global rows 32..63
  if (r0 >= 32) {
#pragma unroll
    for (int i = 0; i < 8; i++) {
      *(float4*)&red[w*2048 + (r0-32+i)*64 + c0    ] = make_float4(accG[i][0],accG[i][1],accG[i][2],accG[i][3]);
      *(float4*)&red[w*2048 + (r0-32+i)*64 + c0 + 4] = make_float4(accG[i][4],accG[i][5],accG[i][6],accG[i][7]);
    }
  }
  __syncthreads();
#pragma unroll
  for (int pp = 0; pp < 2; pp++) {
    int fi = t + pp*256;
    float4 s0 = redf4[fi], s1 = redf4[512+fi], s2 = redf4[1024+fi], s3 = redf4[1536+fi];
    float4 r; r.x = s0.x+s1.x+s2.x+s3.x; r.y = s0.y+s1.y+s2.y+s3.y;
    r.z = s0.z+s1.z+s2.z+s3.z; r.w = s0.w+s1.w+s2.w+s3.w;
    *(float4*)&gout[2048 + fi*4] = r;
  }
  __syncthreads();
  // sum-of-squares partials
  redf4[w*64 + lane]       = make_float4(sqq[0],sqq[1],sqq[2],sqq[3]);
  redf4[256 + w*64 + lane] = make_float4(sqk[0],sqk[1],sqk[2],sqk[3]);
  __syncthreads();
  if (t < 128) {
    const int d = t & 63;
    const int col4 = d >> 2, c = d & 3;
    const int base = (t < 64) ? 0 : 1024;   // float offset into red
    float s = 0.f;
#pragma unroll
    for (int ww = 0; ww < 4; ww++)
#pragma unroll
      for (int m = 0; m < 4; m++)
        s += red[base + (ww*64 + m*16 + col4)*4 + c];
    float* dst = (t < 64) ? qsqp : ksqp;
    dst[((size_t)bh*NCH + cx)*64 + d] = s;
  }
}

// ---------------------------------------------------------------------------
// Kernel B: reduce partials, then per (b,h) 64x64 postprocessing: normalize,
// gates, temperature, 4x exact top-k (rank counting) + masked softmax -> M.
// ---------------------------------------------------------------------------
__global__ __launch_bounds__(256) void mask_kernel(
    const float* __restrict__ Gp, const float* __restrict__ qsqp,
    const float* __restrict__ ksqp,
    const float* __restrict__ temperature, const float* __restrict__ attns,
    const float* __restrict__ row_w, const float* __restrict__ row_b,
    const float* __restrict__ col_w, const float* __restrict__ col_b,
    float* __restrict__ M)
{
  const int bh = blockIdx.x;
  const int h = bh & 7;
  const int t = threadIdx.x;
  const int d = t & 63, q4 = t >> 6;
  const int e0 = q4 * 16;

  __shared__ float att[64][65];
  __shared__ float rnq[64], rnk[64], cw[64], rw[64];
  __shared__ float wcol[64], wrow[64];
  __shared__ float thr[4][64];
  __shared__ float pmax[4][64];
  __shared__ float rowmax[64];
  __shared__ float psum[4][4][64];
  __shared__ float rinv[4][64];

  if (t < 64) {
    float s = 0.f;
    for (int c = 0; c < NCH; c++) s += qsqp[((size_t)bh*NCH + c)*64 + t];
    rnq[t] = 1.0f / fmaxf(sqrtf(s), 1e-12f);
  } else if (t < 128) {
    float s = 0.f;
    for (int c = 0; c < NCH; c++) s += ksqp[((size_t)bh*NCH + c)*64 + (t-64)];
    rnk[t-64] = 1.0f / fmaxf(sqrtf(s), 1e-12f);
  } else if (t < 192) {
    cw[t-128] = col_w[t-128];
  } else {
    rw[t-192] = row_w[t-192];
  }
  __syncthreads();

  {
    const float rq = rnq[d];
#pragma unroll
    for (int ee = 0; ee < 16; ee += 4) {
      float4 g = make_float4(0.f,0.f,0.f,0.f);
      for (int c = 0; c < NCH; c++) {
        float4 gc = *(const float4*)&Gp[((size_t)bh*NCH + c)*4096 + d*64 + e0 + ee];
        g.x += gc.x; g.y += gc.y; g.z += gc.z; g.w += gc.w;
      }
      att[d][e0+ee+0] = g.x * rq * rnk[e0+ee+0];
      att[d][e0+ee+1] = g.y * rq * rnk[e0+ee+1];
      att[d][e0+ee+2] = g.z * rq * rnk[e0+ee+2];
      att[d][e0+ee+3] = g.w * rq * rnk[e0+ee+3];
    }
  }
  __syncthreads();

  if (t < 64) {
    float s = 0.f;
    for (int c = 0; c < 64; c++) s += att[c][t] * cw[c];
    s += col_b[0];
    wcol[t] = 1.0f / (1.0f + __expf(-s));
  } else if (t < 128) {
    int c = t - 64;
    float s = 0.f;
    for (int e = 0; e < 64; e++) s += att[c][e] * rw[e];
    s += row_b[0];
    wrow[c] = 1.0f / (1.0f + __expf(-s));
  }
  __syncthreads();

  {
    const float temp = temperature[h];
    const float wr = wrow[d];
    float mx = -1e30f;
#pragma unroll
    for (int ee = 0; ee < 16; ee++) {
      float x = att[d][e0+ee] * ((wcol[e0+ee] + wr) * temp);
      att[d][e0+ee] = x;
      mx = fmaxf(mx, x);
    }
    pmax[q4][d] = mx;
  }
  __syncthreads();
  if (t < 64)
    rowmax[t] = fmaxf(fmaxf(pmax[0][t], pmax[1][t]), fmaxf(pmax[2][t], pmax[3][t]));

  // exact k-th largest by rank counting (tie-exact like lax.top_k)
  {
    float x[16];
#pragma unroll
    for (int j = 0; j < 16; j++) x[j] = att[d][e0+j];
    int gt[16] = {}, ge[16] = {};
    for (int m = 0; m < 64; m++) {
      float y = att[d][m];
#pragma unroll
      for (int j = 0; j < 16; j++) { gt[j] += (y > x[j]); ge[j] += (y >= x[j]); }
    }
    const int tks[4] = {32, 42, 48, 51};
#pragma unroll
    for (int j = 0; j < 16; j++)
#pragma unroll
      for (int i = 0; i < 4; i++)
        if (gt[j] <= tks[i]-1 && ge[j] >= tks[i]) thr[i][d] = x[j];
  }
  __syncthreads();

  {
    const float rm = rowmax[d];
    const float t0 = thr[0][d], t1 = thr[1][d], t2 = thr[2][d], t3 = thr[3][d];
    float s0=0.f, s1=0.f, s2=0.f, s3=0.f;
#pragma unroll
    for (int ee = 0; ee < 16; ee++) {
      float xv = att[d][e0+ee];
      float ex = __expf(xv - rm);
      if (xv >= t0) s0 += ex;
      if (xv >= t1) s1 += ex;
      if (xv >= t2) s2 += ex;
      if (xv >= t3) s3 += ex;
    }
    psum[q4][0][d] = s0; psum[q4][1][d] = s1; psum[q4][2][d] = s2; psum[q4][3][d] = s3;
  }
  __syncthreads();
  if (t < 64) {
#pragma unroll
    for (int i = 0; i < 4; i++) {
      float s = psum[0][i][t] + psum[1][i][t] + psum[2][i][t] + psum[3][i][t];
      rinv[i][t] = attns[i] / s;
    }
  }
  __syncthreads();

  {
    const float rm = rowmax[d];
    const float t0 = thr[0][d], t1 = thr[1][d], t2 = thr[2][d], t3 = thr[3][d];
    const float r0 = rinv[0][d], r1 = rinv[1][d], r2 = rinv[2][d], r3 = rinv[3][d];
    float* mo = M + (size_t)bh*4096 + d*64 + e0;
#pragma unroll
    for (int ee = 0; ee < 16; ee++) {
      float xv = att[d][e0+ee];
      float ex = __expf(xv - rm);
      float m = 0.f;
      if (xv >= t0) m += r0 * ex;
      if (xv >= t1) m += r1 * ex;
      if (xv >= t2) m += r2 * ex;
      if (xv >= t3) m += r3 * ex;
      mo[ee] = m;
    }
  }
}

// ---------------------------------------------------------------------------
// Kernel C: out[b,l,h,:] = M_bh * v[b,l,h,:].  One 64-l tile per block
// (R1 structure — fastest so far).
// ---------------------------------------------------------------------------
__global__ __launch_bounds__(256) void apply_kernel(
    const float* __restrict__ M, const float* __restrict__ v,
    float* __restrict__ out)
{
  const int bh = blockIdx.y;
  const int b = bh >> 3, h = bh & 7;
  const int l0 = blockIdx.x * 64;
  const int t = threadIdx.x;

  __shared__ float Ms[64][68];   // [e][d]
  __shared__ float Vs[64][68];   // [l][e]

#pragma unroll
  for (int i = 0; i < 4; i++) {
    int idx = t + i*256;
    int dd = idx >> 4;
    int c4 = (idx & 15) * 4;
    float4 mv = *(const float4*)(M + (size_t)bh*4096 + dd*64 + c4);
    Ms[c4+0][dd] = mv.x; Ms[c4+1][dd] = mv.y; Ms[c4+2][dd] = mv.z; Ms[c4+3][dd] = mv.w;
    float4 vv = *(const float4*)(v + (((size_t)b*L_ + l0 + dd)*H_ + h)*D_ + c4);
    *(float4*)&Vs[dd][c4] = vv;
  }
  __syncthreads();

  const int dq = t & 15, lq = t >> 4;
  const int d0 = dq * 4, lr = lq * 4;
  float acc[4][4] = {};

#pragma unroll
  for (int e4 = 0; e4 < 16; e4++) {
    const int e = e4 * 4;
    float4 m0 = *(const float4*)&Ms[e+0][d0];
    float4 m1 = *(const float4*)&Ms[e+1][d0];
    float4 m2 = *(const float4*)&Ms[e+2][d0];
    float4 m3 = *(const float4*)&Ms[e+3][d0];
    float ma[4][4] = {{m0.x,m0.y,m0.z,m0.w},{m1.x,m1.y,m1.z,m1.w},
                      {m2.x,m2.y,m2.z,m2.w},{m3.x,m3.y,m3.z,m3.w}};
#pragma unroll
    for (int j = 0; j < 4; j++) {
      float4 vj = *(const float4*)&Vs[lr+j][e];
      float va[4] = {vj.x, vj.y, vj.z, vj.w};
#pragma unroll
      for (int i = 0; i < 4; i++) {
        acc[i][j] = fmaf(ma[0][i], va[0], acc[i][j]);
        acc[i][j] = fmaf(ma[1][i], va[1], acc[i][j]);
        acc[i][j] = fmaf(ma[2][i], va[2], acc[i][j]);
        acc[i][j] = fmaf(ma[3][i], va[3], acc[i][j]);
      }
    }
  }

#pragma unroll
  for (int j = 0; j < 4; j++) {
    int l = l0 + lr + j;
    float4 o = make_float4(acc[0][j], acc[1][j], acc[2][j], acc[3][j]);
    *(float4*)(out + (((size_t)b*L_ + l)*H_ + h)*D_ + d0) = o;
  }
}

// ---------------------------------------------------------------------------
extern "C" void kernel_launch(void* const* d_in, const int* in_sizes, int n_in,
                              void* d_out, int out_size, void* d_ws, size_t ws_size,
                              hipStream_t stream) {
  const float* q           = (const float*)d_in[0];
  const float* k           = (const float*)d_in[1];
  const float* v           = (const float*)d_in[2];
  const float* temperature = (const float*)d_in[3];
  const float* attns       = (const float*)d_in[4];
  const float* row_w       = (const float*)d_in[5];
  const float* row_b       = (const float*)d_in[6];
  const float* col_w       = (const float*)d_in[7];
  const float* col_b       = (const float*)d_in[8];
  float* out = (float*)d_out;

  float* ws   = (float*)d_ws;
  float* Gp   = ws;
  float* qsqp = ws + QSQP_OFF;
  float* ksqp = ws + KSQP_OFF;
  float* M    = ws + M_OFF;

  // no memset needed: all workspace regions are fully written before read

  gram_kernel<<<dim3(NCH, BH_), 256, 0, stream>>>(q, k, Gp, qsqp, ksqp);
  mask_kernel<<<dim3(BH_), 256, 0, stream>>>(Gp, qsqp, ksqp, temperature, attns,
                                             row_w, row_b, col_w, col_b, M);
  apply_kernel<<<dim3(L_/64, BH_), 256, 0, stream>>>(M, v, out);
}